// Round 7
// baseline (347.387 us; speedup 1.0000x reference)
//
#include <hip/hip_runtime.h>
#include <hip/hip_bf16.h>
#include <hip/hip_fp16.h>

typedef __attribute__((ext_vector_type(8))) short short8;
typedef __attribute__((ext_vector_type(4))) float f32x4;

#define DEVI __device__ __forceinline__

DEVI unsigned short f2bf(float f){
  __hip_bfloat16 h = __float2bfloat16(f);
  unsigned short u; __builtin_memcpy(&u, &h, 2); return u;
}

// ---------------- cast fp32 -> bf16 ----------------
__global__ void cast_f32_bf16(const float* __restrict__ in, unsigned short* __restrict__ out, int n4){
  int stride = gridDim.x * blockDim.x;
  for (int i = blockIdx.x*blockDim.x + threadIdx.x; i < n4; i += stride){
    float4 f = reinterpret_cast<const float4*>(in)[i];
    ushort4 o;
    o.x = f2bf(f.x); o.y = f2bf(f.y); o.z = f2bf(f.z); o.w = f2bf(f.w);
    reinterpret_cast<ushort4*>(out)[i] = o;
  }
}

// ---------------- transpose + cast: WT[n][k] = W[k][n] ----------------
__global__ void transpose_cast_w(const float* __restrict__ W, unsigned short* __restrict__ WT, int K, int N){
  __shared__ float tile[32][33];
  int bn = blockIdx.x*32, bk = blockIdx.y*32;
  int tx = threadIdx.x & 31, ty = threadIdx.x >> 5;
  for (int r=0;r<32;r+=8)
    tile[ty+r][tx] = W[(long)(bk+ty+r)*N + bn+tx];
  __syncthreads();
  for (int r=0;r<32;r+=8)
    WT[(long)(bn+ty+r)*K + bk+tx] = (short)f2bf(tile[tx][ty+r]);
}

// ---------------- async global->LDS, 16B/lane ----------------
DEVI void stage16(const short* gsrc, short* lbase){
  __builtin_amdgcn_global_load_lds(
      (const __attribute__((address_space(1))) unsigned int*)gsrc,
      (__attribute__((address_space(3))) unsigned int*)lbase, 16, 0, 0);
}

// Stage one 16KB K-half block (256 rows x 32 kelems), 2 loads/thread.
DEVI void stage2(const short* base, long o0, long o1, short* blk, int w){
  stage16(base + o0, blk + w*512);
  stage16(base + o1, blk + (8+w)*512);
}

// ---------------- 256x256 8-phase GEMM body (exact m201 ledger) -------------
// OT: 0=f32, 1=f16, 2=bf16.  BIAS: 0 none, 1 per-col, 2 per-row.
// BK=64 (2 K-halves), 512 thr = 8 waves (2M x 4N), dbuf LDS 128KB.
// LDS block (shorts): buf*32768 + op*16384 + khalf*8192  (op 0=A,1=B).
// Phase = {reads for THIS phase's MFMA (8 or 4); stage 1 half (2 loads);
//          [lgkm(4) if 8 reads]; barrier; lgkm(0); sched_barrier; setprio(1);
//          16 MFMA (one m-quadrant x one k-step); setprio(0);
//          [vmcnt(6) at phases 4&8 only]; barrier}.
// Stage stream: 1 half/phase, 3 halves (6 loads) in flight at tile ends;
// every staged half lands >=1 tile-boundary vmcnt(6) before its first read;
// every stage targets the block last-read exactly 1 phase earlier (drained
// at that phase's pre-MFMA lgkm(0)).
template<int OT, int BIAS>
DEVI void gemm8_body(const short* __restrict__ A, const short* __restrict__ Bt,
                     const float* __restrict__ bias, void* __restrict__ Cv,
                     int N, int K, long sA, long sB, long sC, float scale, int nx, int ny)
{
  extern __shared__ short lds[];
  // bijective XCD swizzle (all launches have nwg % 8 == 0)
  const int nwg = gridDim.x;
  const int cpx = nwg >> 3;
  const int wg  = (blockIdx.x & 7)*cpx + (blockIdx.x >> 3);
  const int bx  = wg % nx;
  const int tmp = wg / nx;
  const int by  = tmp % ny;
  const long bz = tmp / ny;
  const int m0 = bx * 256, n0 = by * 256;
  const short* Ab = A  + bz*sA + (long)m0 * K;
  const short* Bb = Bt + bz*sB + (long)n0 * K;

  const int t = threadIdx.x, lane = t & 63, w = t >> 6;
  const int wr = w >> 2, wc = w & 3;            // 2M x 4N wave grid

  // staging invariants: chunk rows + pre-swizzled k (st_16x32 involution)
  const int rr = lane >> 2;
  const int kk = ((lane & 3) * 8) ^ ((lane & 32) ? 16 : 0);
  const long off0 = (long)(( w     )*16 + rr) * K + kk;
  const long off1 = (long)(( 8 + w )*16 + rr) * K + kk;

  // ds_read invariants: swizzled per-lane byte offset within each 1KB subtile
  const int la = lane & 15;
  const int lsw = (la*64 + ((lane>>4)<<4)) ^ ((la>=8)?32:0);
  const short* AP = lds + (lsw>>1) + wr*4096;           // + qm*2048 + rb*512
  const short* BP = lds + (lsw>>1) + 16384 + wc*2048;   // + c*512

  f32x4 acc[8][4] = {};
  short8 b0,b1,b2,b3;                                   // B held across QM0->QM1

  const int NT = K >> 6;          // K-tiles of 64
  const int niter = NT >> 1;      // 2 K-tiles per iteration

  // ---- prologue: stream halves s0..s6 ----
  // s: tile=s>>2, ht=s&3 in {Bk0,Ak0,Bk1,Ak1}
  stage2(Bb,      off0, off1, lds + 16384, w);   // t0.Bk0
  stage2(Ab,      off0, off1, lds + 0,     w);   // t0.Ak0
  stage2(Bb + 32, off0, off1, lds + 24576, w);   // t0.Bk1
  stage2(Ab + 32, off0, off1, lds + 8192,  w);   // t0.Ak1
  stage2(Bb + 64, off0, off1, lds + 49152, w);   // t1.Bk0
  stage2(Ab + 64, off0, off1, lds + 32768, w);   // t1.Ak0
  stage2(Bb + 96, off0, off1, lds + 57344, w);   // t1.Bk1
  asm volatile("s_waitcnt vmcnt(6)" ::: "memory");   // t0 fully landed; 3 halves in flight
  asm volatile("s_barrier" ::: "memory");

#define MM16(QM) \
    acc[(QM)*4+0][0] = __builtin_amdgcn_mfma_f32_16x16x32_bf16(a0, b0, acc[(QM)*4+0][0],0,0,0); \
    acc[(QM)*4+0][1] = __builtin_amdgcn_mfma_f32_16x16x32_bf16(a0, b1, acc[(QM)*4+0][1],0,0,0); \
    acc[(QM)*4+0][2] = __builtin_amdgcn_mfma_f32_16x16x32_bf16(a0, b2, acc[(QM)*4+0][2],0,0,0); \
    acc[(QM)*4+0][3] = __builtin_amdgcn_mfma_f32_16x16x32_bf16(a0, b3, acc[(QM)*4+0][3],0,0,0); \
    acc[(QM)*4+1][0] = __builtin_amdgcn_mfma_f32_16x16x32_bf16(a1, b0, acc[(QM)*4+1][0],0,0,0); \
    acc[(QM)*4+1][1] = __builtin_amdgcn_mfma_f32_16x16x32_bf16(a1, b1, acc[(QM)*4+1][1],0,0,0); \
    acc[(QM)*4+1][2] = __builtin_amdgcn_mfma_f32_16x16x32_bf16(a1, b2, acc[(QM)*4+1][2],0,0,0); \
    acc[(QM)*4+1][3] = __builtin_amdgcn_mfma_f32_16x16x32_bf16(a1, b3, acc[(QM)*4+1][3],0,0,0); \
    acc[(QM)*4+2][0] = __builtin_amdgcn_mfma_f32_16x16x32_bf16(a2, b0, acc[(QM)*4+2][0],0,0,0); \
    acc[(QM)*4+2][1] = __builtin_amdgcn_mfma_f32_16x16x32_bf16(a2, b1, acc[(QM)*4+2][1],0,0,0); \
    acc[(QM)*4+2][2] = __builtin_amdgcn_mfma_f32_16x16x32_bf16(a2, b2, acc[(QM)*4+2][2],0,0,0); \
    acc[(QM)*4+2][3] = __builtin_amdgcn_mfma_f32_16x16x32_bf16(a2, b3, acc[(QM)*4+2][3],0,0,0); \
    acc[(QM)*4+3][0] = __builtin_amdgcn_mfma_f32_16x16x32_bf16(a3, b0, acc[(QM)*4+3][0],0,0,0); \
    acc[(QM)*4+3][1] = __builtin_amdgcn_mfma_f32_16x16x32_bf16(a3, b1, acc[(QM)*4+3][1],0,0,0); \
    acc[(QM)*4+3][2] = __builtin_amdgcn_mfma_f32_16x16x32_bf16(a3, b2, acc[(QM)*4+3][2],0,0,0); \
    acc[(QM)*4+3][3] = __builtin_amdgcn_mfma_f32_16x16x32_bf16(a3, b3, acc[(QM)*4+3][3],0,0,0);

// PHASE(BUF, KH, QM, SBASE, SKOFF, SLDS, TAILVM)
//   QM0: read 4 B + 4 A (lgkm(4) pre-barrier); QM1: read 4 A only.
#define PHASE(BUF, KH, QM, SBASE, SKOFF, SLDS, TAILVM) do {                     \
    short8 a0,a1,a2,a3;                                                         \
    const short* ap_ = AP + (BUF)*32768 + (KH)*8192 + (QM)*2048;                \
    if ((QM) == 0){                                                             \
      const short* bp_ = BP + (BUF)*32768 + (KH)*8192;                          \
      b0 = *reinterpret_cast<const short8*>(bp_ + 0*512);                       \
      b1 = *reinterpret_cast<const short8*>(bp_ + 1*512);                       \
      b2 = *reinterpret_cast<const short8*>(bp_ + 2*512);                       \
      b3 = *reinterpret_cast<const short8*>(bp_ + 3*512);                       \
    }                                                                           \
    a0 = *reinterpret_cast<const short8*>(ap_ + 0*512);                         \
    a1 = *reinterpret_cast<const short8*>(ap_ + 1*512);                         \
    a2 = *reinterpret_cast<const short8*>(ap_ + 2*512);                         \
    a3 = *reinterpret_cast<const short8*>(ap_ + 3*512);                         \
    stage2((SBASE) + (SKOFF), off0, off1, lds + (SLDS), w);                     \
    if ((QM) == 0) asm volatile("s_waitcnt lgkmcnt(4)" ::: "memory");           \
    asm volatile("s_barrier" ::: "memory");                                     \
    asm volatile("s_waitcnt lgkmcnt(0)" ::: "memory");                          \
    __builtin_amdgcn_sched_barrier(0);                                          \
    __builtin_amdgcn_s_setprio(1);                                              \
    MM16(QM)                                                                    \
    __builtin_amdgcn_s_setprio(0);                                              \
    if (TAILVM) asm volatile("s_waitcnt vmcnt(6)" ::: "memory");                \
    asm volatile("s_barrier" ::: "memory");                                     \
  } while(0)

  for (int it = 0; it < niter; ++it){
    const int u  = it*2;
    int u1 = u+1; if (u1 >= NT) u1 -= NT;
    int u2 = u+2; if (u2 >= NT) u2 -= NT;
    int u3 = u+3; if (u3 >= NT) u3 -= NT;
    const int k1 = u1*64, k2 = u2*64, k3 = u3*64;
    // tile u (buf0):
    PHASE(0,0,0, Ab, k1+32, 40960, 0);   // stage t(u1).Ak1 -> buf1.A.k1
    PHASE(0,0,1, Bb, k2,    16384, 0);   // stage t(u2).Bk0 -> buf0.B.k0
    PHASE(0,1,0, Ab, k2,    0,     0);   // stage t(u2).Ak0 -> buf0.A.k0
    PHASE(0,1,1, Bb, k2+32, 24576, 1);   // stage t(u2).Bk1 -> buf0.B.k1; vmcnt(6)
    // tile u+1 (buf1):
    PHASE(1,0,0, Ab, k2+32, 8192,  0);   // stage t(u2).Ak1 -> buf0.A.k1
    PHASE(1,0,1, Bb, k3,    49152, 0);   // stage t(u3).Bk0 -> buf1.B.k0
    PHASE(1,1,0, Ab, k3,    32768, 0);   // stage t(u3).Ak0 -> buf1.A.k0
    PHASE(1,1,1, Bb, k3+32, 57344, 1);   // stage t(u3).Bk1 -> buf1.B.k1; vmcnt(6)
  }
#undef PHASE
#undef MM16

  // drain outstanding staging before reusing LDS for the epilogue
  asm volatile("s_waitcnt vmcnt(0) lgkmcnt(0)" ::: "memory");
  __syncthreads();

  // ---- epilogue: coalesce through LDS (XOR-swizzled 32-row staging) ----
  {
    char* sb = (char*)lds;
    constexpr int STRB = (OT==0) ? 1056 : 544;   // row stride bytes (pad chunks)
    const int tr = t >> 4, tcE = (t & 15) * 16;
    const int grow = m0 + (tr>>4)*128 + (tr&15); // + mi*16 added per mi
    #pragma unroll
    for (int mi = 0; mi < 8; ++mi){
      __syncthreads();
      #pragma unroll
      for (int nj = 0; nj < 4; ++nj){
        const int c = wc*64 + la + nj*16;
        float badd = (BIAS==1) ? bias[n0 + c] : 0.0f;
        #pragma unroll
        for (int j = 0; j < 4; ++j){
          const int lr = wr*16 + ((lane>>4)<<2) + j;
          float v = acc[mi][nj][j] * scale + badd;
          if (BIAS==2) v += bias[m0 + (lr>>4)*128 + mi*16 + (lr&15)];
          if constexpr (OT==0){
            const int byte = lr*STRB + ((((c>>2) ^ (lr&15)))<<4) + (c&3)*4;
            *reinterpret_cast<float*>(sb + byte) = v;
          } else if constexpr (OT==1){
            const int byte = lr*STRB + ((((c>>3) ^ (lr&15)))<<4) + (c&7)*2;
            *reinterpret_cast<__half*>(sb + byte) = __float2half(v);
          } else {
            const int byte = lr*STRB + ((((c>>3) ^ (lr&15)))<<4) + (c&7)*2;
            *reinterpret_cast<unsigned short*>(sb + byte) = f2bf(v);
          }
        }
      }
      __syncthreads();
      const long gbase = bz*sC + (long)(grow + mi*16)*N + n0 + tcE;
      if constexpr (OT==0){
        const int cb = tcE >> 2;
        #pragma unroll
        for (int i=0;i<4;i++){
          f32x4 vv = *reinterpret_cast<const f32x4*>(sb + tr*STRB + (((cb+i)^(tr&15))<<4));
          *reinterpret_cast<f32x4*>((float*)Cv + gbase + i*4) = vv;
        }
      } else {
        const int cb = tcE >> 3;
        #pragma unroll
        for (int i=0;i<2;i++){
          short8 vv = *reinterpret_cast<const short8*>(sb + tr*STRB + (((cb+i)^(tr&15))<<4));
          *reinterpret_cast<short8*>((unsigned short*)Cv + gbase + i*8) = vv;
        }
      }
    }
  }
}

#define GATTR __global__ __attribute__((amdgpu_flat_work_group_size(512,512), amdgpu_waves_per_eu(2,2)))
// named wrappers for per-stage rocprof attribution
GATTR void g_proj_k(const short* A, const short* Bt, const float* bias, void* Cv,
                    int N, int K, long sA, long sB, long sC, float scale, int nx, int ny)
{ gemm8_body<2,1>(A,Bt,bias,Cv,N,K,sA,sB,sC,scale,nx,ny); }
GATTR void g_proj_v(const short* A, const short* Bt, const float* bias, void* Cv,
                    int N, int K, long sA, long sB, long sC, float scale, int nx, int ny)
{ gemm8_body<2,2>(A,Bt,bias,Cv,N,K,sA,sB,sC,scale,nx,ny); }
GATTR void g_proj_q(const short* A, const short* Bt, const float* bias, void* Cv,
                    int N, int K, long sA, long sB, long sC, float scale, int nx, int ny)
{ gemm8_body<2,1>(A,Bt,bias,Cv,N,K,sA,sB,sC,scale,nx,ny); }
GATTR void g_score(const short* A, const short* Bt, const float* bias, void* Cv,
                   int N, int K, long sA, long sB, long sC, float scale, int nx, int ny)
{ gemm8_body<1,0>(A,Bt,bias,Cv,N,K,sA,sB,sC,scale,nx,ny); }
GATTR void g_pv(const short* A, const short* Bt, const float* bias, void* Cv,
                int N, int K, long sA, long sB, long sC, float scale, int nx, int ny)
{ gemm8_body<0,0>(A,Bt,bias,Cv,N,K,sA,sB,sC,scale,nx,ny); }

// ---------------- row softmax, fp16 in -> bf16 out, in place ----------------
__global__ void softmax_rows(unsigned short* __restrict__ SP, int cols){
  const long row = blockIdx.x;
  unsigned short* rp = SP + row * cols;
  const int t = threadIdx.x, lane = t & 63, w = t >> 6;
  short8 raw = *reinterpret_cast<const short8*>(rp + t*8);
  float v[8];
  #pragma unroll
  for (int i=0;i<8;i++){
    unsigned short us = (unsigned short)raw[i];
    __half h; __builtin_memcpy(&h, &us, 2);
    v[i] = __half2float(h);
  }
  float m = v[0];
  #pragma unroll
  for (int i=1;i<8;i++) m = fmaxf(m, v[i]);
  #pragma unroll
  for (int o=32;o;o>>=1) m = fmaxf(m, __shfl_down(m, o));
  __shared__ float red[8];
  if (lane==0) red[w] = m;
  __syncthreads();
  if (t==0) red[4] = fmaxf(fmaxf(red[0],red[1]), fmaxf(red[2],red[3]));
  __syncthreads();
  const float rowmax = red[4];
  float s = 0.f;
  #pragma unroll
  for (int i=0;i<8;i++){ v[i] = __expf(v[i]-rowmax); s += v[i]; }
  #pragma unroll
  for (int o=32;o;o>>=1) s += __shfl_down(s, o);
  if (lane==0) red[w] = s;
  __syncthreads();
  if (t==0) red[5] = red[0]+red[1]+red[2]+red[3];
  __syncthreads();
  const float inv = 1.0f / red[5];
  short8 outp;
  #pragma unroll
  for (int i=0;i<8;i++) outp[i] = (short)f2bf(v[i]*inv);
  *reinterpret_cast<short8*>(rp + t*8) = outp;
}

extern "C" void kernel_launch(void* const* d_in, const int* in_sizes, int n_in,
                              void* d_out, int out_size, void* d_ws, size_t ws_size,
                              hipStream_t stream)
{
  const int B = 8, S = 2048, D = 1024;
  const int BS = B * S;                      // 16384
  const float* x1 = (const float*)d_in[0];
  const float* x2 = (const float*)d_in[1];
  const float* Wq = (const float*)d_in[2];
  const float* bq = (const float*)d_in[3];
  const float* Wk = (const float*)d_in[4];
  const float* bk = (const float*)d_in[5];
  const float* Wv = (const float*)d_in[6];
  const float* bv = (const float*)d_in[7];

  char* ws = (char*)d_ws;
  const size_t MB = 1024*1024;
  short*          x1b = (short*)(ws);             // 32MB (dead after q GEMM)
  short*          x2b = (short*)(ws + 32*MB);     // 32MB (dead after vT GEMM)
  unsigned short* Sc  = (unsigned short*)ws;      // 64MB scores/probs (reuses x1b/x2b)
  short*          q   = (short*)(ws + 64*MB);     // 32MB
  short*          k   = (short*)(ws + 96*MB);     // 32MB
  short*          vT  = (short*)(ws + 128*MB);    // 32MB [B][D][S]
  short*          WqT = (short*)(ws + 160*MB);
  short*          WkT = (short*)(ws + 162*MB);
  short*          WvT = (short*)(ws + 164*MB);    // total 166MB

  const size_t SH = 131072;  // 128KB dynamic LDS

  cast_f32_bf16<<<4096,256,0,stream>>>(x2, (unsigned short*)x2b, BS*D/4);
  transpose_cast_w<<<dim3(32,32),256,0,stream>>>(Wk, (unsigned short*)WkT, D, D);
  transpose_cast_w<<<dim3(32,32),256,0,stream>>>(Wv, (unsigned short*)WvT, D, D);
  // k2 = x2 @ Wk + bk (bf16): M=BS,N=D,K=D; grid 64x4 = 256
  g_proj_k<<<256, 512, SH, stream>>>(x2b, WkT, bk, k, D, D, 0,0,0, 1.0f, 64, 4);
  // vT[b] = WvT @ x2[b]^T + bv(per-row): M=D,N=S,K=D; grid 4x8x8 = 256
  g_proj_v<<<256, 512, SH, stream>>>(WvT, x2b, bv, vT, S, D, 0, (long)S*D, (long)D*S, 1.0f, 4, 8);
  cast_f32_bf16<<<4096,256,0,stream>>>(x1, (unsigned short*)x1b, BS*D/4);
  transpose_cast_w<<<dim3(32,32),256,0,stream>>>(Wq, (unsigned short*)WqT, D, D);
  // q1 = x1 @ Wq + bq: grid 256
  g_proj_q<<<256, 512, SH, stream>>>(x1b, WqT, bq, q, D, D, 0,0,0, 1.0f, 64, 4);
  // scores = q k^T / 32 (fp16): M=S,N=S,K=D; grid 8x8x8 = 512
  g_score<<<512, 512, SH, stream>>>(q, k, nullptr, Sc, S, D,
                                    (long)S*D, (long)S*D, (long)S*S, 0.03125f, 8, 8);
  // softmax rows, in place -> bf16 probs
  softmax_rows<<<BS,256,0,stream>>>(Sc, S);
  // O = P @ V: A=P[S,S] bf16, Bt=vT[D,S], C=f32 out: M=S,N=D,K=S; grid 8x4x8 = 256
  g_pv<<<256, 512, SH, stream>>>((short*)Sc, vT, nullptr, d_out, D, S,
                                 (long)S*S, (long)D*S, (long)S*D, 1.0f, 8, 4);
}